// Round 7
// baseline (388.450 us; speedup 1.0000x reference)
//
#include <hip/hip_runtime.h>

// Problem constants: B=32, S=4096, H=512, E=512
typedef __attribute__((ext_vector_type(8))) short bf16x8;
typedef __attribute__((ext_vector_type(16))) float f32x16;

union frag_u { bf16x8 v; unsigned int u[4]; };

__device__ inline unsigned int cvt_pk_bf16(float lo, float hi){
  unsigned int r;
  asm("v_cvt_pk_bf16_f32 %0, %1, %2" : "=v"(r) : "v"(lo), "v"(hi));
  return r;
}
__device__ inline float fast_tanh(float x){
  float e = __builtin_amdgcn_exp2f(x * 2.8853900817779268f);
  return 1.0f - 2.0f * __builtin_amdgcn_rcpf(e + 1.0f);
}
// Pin a fragment into registers: 4 scalar tied operands (128-bit tied
// operands are unsupported by the backend). Forces residency; blocks
// rematerialization from the load origin.
#define PIN8(F) asm volatile("" : "+v"((F).u[0]), "+v"((F).u[1]), \
                                  "+v"((F).u[2]), "+v"((F).u[3]))

// ---- K0: We [512][512] f32 -> bf16 fragment images for mfma_32x32x16.
// Record (nc,t,lane), 16B: col = nc*32+(lane&31), k = t*16+(lane>>5)*8+j.
// Chunk nc's image = 32 KB, lane-linear -> coalesced 1KB/wave loads,
// L1-resident while a chunk is hot.
__global__ __launch_bounds__(256) void we_conv(const float* __restrict__ We,
                                               uint4* __restrict__ weFrag){
  int gid = blockIdx.x * 256 + threadIdx.x;   // 32768 = 16 nc x 32 t x 64 lanes
  int l  = gid & 63;
  int nc = gid >> 11;
  int t  = (gid >> 6) & 31;
  int colv = nc*32 + (l & 31);
  int k = t*16 + (l >> 5)*8;
  const float4* src = (const float4*)(We + colv*512 + k);
  float4 f0 = src[0], f1 = src[1];
  weFrag[gid] = make_uint4(cvt_pk_bf16(f0.x,f0.y), cvt_pk_bf16(f0.z,f0.w),
                           cvt_pk_bf16(f1.x,f1.y), cvt_pk_bf16(f1.z,f1.w));
}

// ---- K1: gd[b][k] = h[b,:]·Wd[k,:] + bd[k] + be[k]
__global__ __launch_bounds__(256) void gd_kernel(const float* __restrict__ hvec,
                                                 const float* __restrict__ Wd,
                                                 const float* __restrict__ bd,
                                                 const float* __restrict__ be,
                                                 float* __restrict__ gd){
  __shared__ float hs[512];
  int b = blockIdx.x >> 2, kc = blockIdx.x & 3;
  int tid = threadIdx.x;
  hs[tid]       = hvec[b*512 + tid];
  hs[tid + 256] = hvec[b*512 + 256 + tid];
  __syncthreads();
  int k  = kc*128 + (tid >> 1);
  int hh = (tid & 1) * 256;
  const float4* wrow = (const float4*)(Wd + (size_t)k*512 + hh);
  const float4* hv4  = (const float4*)(hs + hh);
  float acc = 0.f;
  #pragma unroll 8
  for (int i = 0; i < 64; ++i){
    float4 w = wrow[i]; float4 u = hv4[i];
    acc += w.x*u.x + w.y*u.y + w.z*u.z + w.w*u.w;
  }
  acc += __shfl_xor(acc, 1);
  if ((tid & 1) == 0) gd[b*512 + k] = acc + bd[k] + be[k];
}

// ---- K2: fused scores. 4 waves x 64 rows = 256 rows/block, 512 blocks.
// 1 wave/SIMD (VGPR ~380): A fully register-resident (64 rows x k512 bf16 =
// 256 VGPR, pinned). NO barriers in the main loop, NO LDS B-staging: B-frags
// stream from the L2/L1-resident weFrag image, group-of-4 pipelined one
// group ahead; each B-frag feeds TWO MFMAs (row-tiles Lo/Hi) -> per-wave
// issue-dense (2048 MFMA cyc/chunk). A staged coalesced via LDS transpose
// (one wave-round at a time, bf16, XOR-swizzled).
__global__ __launch_bounds__(256, 1) void score_kernel(
    const float* __restrict__ ctx, const uint4* __restrict__ weFrag,
    const float* __restrict__ gd, const float* __restrict__ Wv,
    float* __restrict__ scores){
  __shared__ char lds[65536];                // A-stage scratch: [64][1024B]

  const int tid  = threadIdx.x;
  const int wid  = tid >> 6;
  const int lane = tid & 63;
  const int bid  = blockIdx.x;
  const int row0 = bid * 256;
  const int b    = bid >> 4;                 // 16 blocks per batch row
  const int col  = lane & 31;
  const int hi   = lane >> 5;

  frag_u af0[32], af1[32];                   // rows +0..31 / +32..63, k-step t

  // ---- A-stage: 4 rounds; round w stages rows row0+w*64.. coalesced into
  // LDS bf16 (swizzled), wave w transposes its 64 fragments into registers.
  for (int w = 0; w < 4; ++w){
    const float* srcBase = ctx + (size_t)(row0 + w*64) * 512;
    #pragma unroll
    for (int i = 0; i < 16; ++i){
      int idx = i*256 + tid;                 // 64 rows x 64 chunks of 8 f32
      int r = idx >> 6, c8 = idx & 63;
      const float4* s4 = (const float4*)(srcBase + r*512 + c8*8);
      float4 f0 = s4[0], f1 = s4[1];
      unsigned int p0 = cvt_pk_bf16(f0.x, f0.y);
      unsigned int p1 = cvt_pk_bf16(f0.z, f0.w);
      unsigned int p2 = cvt_pk_bf16(f1.x, f1.y);
      unsigned int p3 = cvt_pk_bf16(f1.z, f1.w);
      int byte = (c8*16) ^ ((r & 7) << 4);
      *(uint4*)(lds + r*1024 + byte) = make_uint4(p0, p1, p2, p3);
    }
    __syncthreads();
    if (wid == w){
      #pragma unroll
      for (int t = 0; t < 32; ++t){
        int r0 = lane & 31;
        int r1 = 32 + r0;
        int byte = t*32 + hi*16;
        af0[t].v = *(const bf16x8*)(lds + r0*1024 + (byte ^ ((r0 & 7) << 4)));
        af1[t].v = *(const bf16x8*)(lds + r1*1024 + (byte ^ ((r1 & 7) << 4)));
        PIN8(af0[t]); PIN8(af1[t]);
      }
    }
    __syncthreads();
  }

  float sc0[16], sc1[16];
  #pragma unroll
  for (int r = 0; r < 16; ++r){ sc0[r] = 0.f; sc1[r] = 0.f; }

  const char* wfBase = (const char*)weFrag + lane*16;

  for (int nc = 0; nc < 16; ++nc){
    const char* bp = wfBase + (size_t)nc*32768;   // + t*1024 per k-step

    // epilogue operands for this chunk: issue early, covered by MFMA phase
    float gdv = gd[b*512 + nc*32 + col];
    float wvv = Wv[nc*32 + col];

    frag_u c0, c1, c2, c3, n0, n1, n2, n3;
    c0.v = *(const bf16x8*)(bp +  0*1024);
    c1.v = *(const bf16x8*)(bp +  8*1024);
    c2.v = *(const bf16x8*)(bp + 16*1024);
    c3.v = *(const bf16x8*)(bp + 24*1024);
    PIN8(c0); PIN8(c1); PIN8(c2); PIN8(c3);

    f32x16 aLo, aHi;
    #pragma unroll
    for (int r = 0; r < 16; ++r){ aLo[r] = 0.f; aHi[r] = 0.f; }

    #pragma unroll
    for (int g = 0; g < 8; ++g){
      if (g < 7){                            // issue next group's 4 loads
        n0.v = *(const bf16x8*)(bp + (g + 1     )*1024);
        n1.v = *(const bf16x8*)(bp + (g + 1 +  8)*1024);
        n2.v = *(const bf16x8*)(bp + (g + 1 + 16)*1024);
        n3.v = *(const bf16x8*)(bp + (g + 1 + 24)*1024);
      }
      __builtin_amdgcn_s_setprio(1);
      aLo = __builtin_amdgcn_mfma_f32_32x32x16_bf16(af0[g     ].v, c0.v, aLo, 0, 0, 0);
      aHi = __builtin_amdgcn_mfma_f32_32x32x16_bf16(af1[g     ].v, c0.v, aHi, 0, 0, 0);
      aLo = __builtin_amdgcn_mfma_f32_32x32x16_bf16(af0[g +  8].v, c1.v, aLo, 0, 0, 0);
      aHi = __builtin_amdgcn_mfma_f32_32x32x16_bf16(af1[g +  8].v, c1.v, aHi, 0, 0, 0);
      aLo = __builtin_amdgcn_mfma_f32_32x32x16_bf16(af0[g + 16].v, c2.v, aLo, 0, 0, 0);
      aHi = __builtin_amdgcn_mfma_f32_32x32x16_bf16(af1[g + 16].v, c2.v, aHi, 0, 0, 0);
      aLo = __builtin_amdgcn_mfma_f32_32x32x16_bf16(af0[g + 24].v, c3.v, aLo, 0, 0, 0);
      aHi = __builtin_amdgcn_mfma_f32_32x32x16_bf16(af1[g + 24].v, c3.v, aHi, 0, 0, 0);
      __builtin_amdgcn_s_setprio(0);
      if (g < 7){                            // wait AFTER the MFMA cluster
        PIN8(n0); PIN8(n1); PIN8(n2); PIN8(n3);
        c0 = n0; c1 = n1; c2 = n2; c3 = n3;
      }
    }

    // sc += tanh(acc + gd) * Wv   (out col = nc*32 + lane&31)
    #pragma unroll
    for (int r = 0; r < 16; ++r){
      sc0[r] += fast_tanh(aLo[r] + gdv) * wvv;
      sc1[r] += fast_tanh(aHi[r] + gdv) * wvv;
    }
  }

  // reduce over the 32 output columns
  #pragma unroll
  for (int r = 0; r < 16; ++r){
    #pragma unroll
    for (int m = 1; m <= 16; m <<= 1){
      sc0[r] += __shfl_xor(sc0[r], m);
      sc1[r] += __shfl_xor(sc1[r], m);
    }
  }
  if (col == 0){
    float* so = scores + row0 + wid*64 + 4*hi;
    #pragma unroll
    for (int r = 0; r < 16; ++r){
      so[     (r & 3) + 8*(r >> 2)] = sc0[r];  // rows +0..31
      so[32 + (r & 3) + 8*(r >> 2)] = sc1[r];  // rows +32..63
    }
  }
}

// ---- K3: softmax over S=4096 per batch row (bv dropped: shift-invariant)
__global__ __launch_bounds__(256) void softmax_kernel(const float* __restrict__ scores,
                                                      float* __restrict__ weights){
  __shared__ float red[8];
  int b = blockIdx.x, tid = threadIdx.x;
  const float4* src = (const float4*)(scores + b*4096);
  float4* dst = (float4*)(weights + b*4096);
  float4 v[4];
  float m = -1e30f;
  #pragma unroll
  for (int i = 0; i < 4; ++i){
    v[i] = src[tid + i*256];
    m = fmaxf(m, fmaxf(fmaxf(v[i].x, v[i].y), fmaxf(v[i].z, v[i].w)));
  }
  #pragma unroll
  for (int o = 1; o < 64; o <<= 1) m = fmaxf(m, __shfl_xor(m, o));
  if ((tid & 63) == 0) red[tid >> 6] = m;
  __syncthreads();
  m = fmaxf(fmaxf(red[0], red[1]), fmaxf(red[2], red[3]));
  float s = 0.f;
  #pragma unroll
  for (int i = 0; i < 4; ++i){
    v[i].x = __builtin_amdgcn_exp2f((v[i].x - m) * 1.4426950408889634f);
    v[i].y = __builtin_amdgcn_exp2f((v[i].y - m) * 1.4426950408889634f);
    v[i].z = __builtin_amdgcn_exp2f((v[i].z - m) * 1.4426950408889634f);
    v[i].w = __builtin_amdgcn_exp2f((v[i].w - m) * 1.4426950408889634f);
    s += v[i].x + v[i].y + v[i].z + v[i].w;
  }
  #pragma unroll
  for (int o = 1; o < 64; o <<= 1) s += __shfl_xor(s, o);
  if ((tid & 63) == 0) red[4 + (tid >> 6)] = s;
  __syncthreads();
  s = red[4] + red[5] + red[6] + red[7];
  float inv = 1.0f / s;
  #pragma unroll
  for (int i = 0; i < 4; ++i){
    v[i].x *= inv; v[i].y *= inv; v[i].z *= inv; v[i].w *= inv;
    dst[tid + i*256] = v[i];
  }
}

// ---- K4: c_t partials (deterministic two-stage, no float atomics)
__global__ __launch_bounds__(256) void ct_partial(const float* __restrict__ ctx,
                                                  const float* __restrict__ wbuf,
                                                  float* __restrict__ part){
  int bid = blockIdx.x;            // 512: b = bid>>4, 256-row s-chunk = bid&15
  int b = bid >> 4, ch = bid & 15;
  int tid = threadIdx.x;
  int hq = tid & 127;
  int sh = tid >> 7;
  const float* wrow = wbuf + b*4096 + ch*256;
  const float4* src = (const float4*)(ctx + ((size_t)b*4096 + (size_t)ch*256)*512) + hq;
  float4 acc = {0.f,0.f,0.f,0.f};
  #pragma unroll 8
  for (int s = sh; s < 256; s += 2){
    float w = wrow[s];
    float4 c = src[(size_t)s*128];
    acc.x += w*c.x; acc.y += w*c.y; acc.z += w*c.z; acc.w += w*c.w;
  }
  ((float4*)(part + (size_t)bid*1024 + sh*512))[hq] = acc;
}

__global__ __launch_bounds__(128) void ct_reduce(const float* __restrict__ part,
                                                 float* __restrict__ ct){
  int b = blockIdx.x, tid = threadIdx.x;
  const float4* p = (const float4*)(part + (size_t)b*16384) + tid;
  float4 acc = {0.f,0.f,0.f,0.f};
  #pragma unroll
  for (int g = 0; g < 32; ++g){
    float4 v = p[g*128];
    acc.x += v.x; acc.y += v.y; acc.z += v.z; acc.w += v.w;
  }
  ((float4*)(ct + b*512))[tid] = acc;
}

// ---- K5: r_t = [c_t,h,x]·Wr^T + br; maxout pairs -> output [32][512]
__global__ __launch_bounds__(256) void final_kernel(
    const float* __restrict__ ct, const float* __restrict__ hvec,
    const float* __restrict__ x, const float* __restrict__ Wr,
    const float* __restrict__ br, float* __restrict__ out){
  __shared__ float xs[8][1536];
  int bt = blockIdx.x >> 4;
  int it = blockIdx.x & 15;
  int tid = threadIdx.x;
  int b0 = bt * 8;
  for (int idx = tid; idx < 8*1536; idx += 256){
    int bl = idx / 1536, j = idx % 1536;
    int b = b0 + bl;
    float v = (j < 512) ? ct[b*512 + j]
            : (j < 1024) ? hvec[b*512 + (j - 512)]
            : x[b*512 + (j - 1024)];
    xs[bl][j] = v;
  }
  __syncthreads();
  int i = it*64 + (tid & 63);
  int bl0 = (tid >> 6) * 2;
  const float4* wrow = (const float4*)(Wr + (size_t)i*1536);
  const float4* x0 = (const float4*)xs[bl0];
  const float4* x1 = (const float4*)xs[bl0 + 1];
  float a0 = 0.f, a1 = 0.f;
  #pragma unroll 4
  for (int k = 0; k < 384; ++k){
    float4 w = wrow[k];
    float4 u0 = x0[k], u1 = x1[k];
    a0 += w.x*u0.x + w.y*u0.y + w.z*u0.z + w.w*u0.w;
    a1 += w.x*u1.x + w.y*u1.y + w.z*u1.z + w.w*u1.w;
  }
  float bias = br[i];
  a0 += bias; a1 += bias;
  float n0 = __shfl_xor(a0, 1);
  float n1 = __shfl_xor(a1, 1);
  if ((tid & 1) == 0){
    out[(b0 + bl0    )*512 + (i >> 1)] = fmaxf(a0, n0);
    out[(b0 + bl0 + 1)*512 + (i >> 1)] = fmaxf(a1, n1);
  }
}

extern "C" void kernel_launch(void* const* d_in, const int* in_sizes, int n_in,
                              void* d_out, int out_size, void* d_ws, size_t ws_size,
                              hipStream_t stream){
  const float* ctx  = (const float*)d_in[0];
  const float* hvec = (const float*)d_in[1];
  const float* x    = (const float*)d_in[2];
  const float* We   = (const float*)d_in[3];
  const float* be   = (const float*)d_in[4];
  const float* Wd   = (const float*)d_in[5];
  const float* bd   = (const float*)d_in[6];
  const float* Wv   = (const float*)d_in[7];
  // d_in[8] = bv: dropped (softmax shift-invariance)
  const float* Wr   = (const float*)d_in[9];
  const float* br   = (const float*)d_in[10];

  float* out     = (float*)d_out;        // output [32][512]
  float* weights = out + 32*512;         // weights [32][4096]

  char* ws = (char*)d_ws;
  char* weFrag  = ws;                                   // 512 KiB
  float* scores = (float*)(ws + (512 << 10));           // 512 KiB
  float* part   = (float*)(ws + (1024 << 10));          // 2 MiB
  float* ct     = (float*)(ws + (3 << 20));             // 64 KiB
  float* gd     = (float*)(ws + (3 << 20) + (64 << 10)); // 64 KiB

  we_conv<<<128, 256, 0, stream>>>(We, (uint4*)weFrag);
  gd_kernel<<<128, 256, 0, stream>>>(hvec, Wd, bd, be, gd);
  score_kernel<<<512, 256, 0, stream>>>(ctx, (const uint4*)weFrag, gd, Wv, scores);
  softmax_kernel<<<32, 256, 0, stream>>>(scores, weights);
  ct_partial<<<512, 256, 0, stream>>>(ctx, weights, part);
  ct_reduce<<<32, 128, 0, stream>>>(part, ct);
  final_kernel<<<64, 256, 0, stream>>>(ct, hvec, x, Wr, br, out);
}

// Round 8
// 201.090 us; speedup vs baseline: 1.9317x; 1.9317x over previous
//
#include <hip/hip_runtime.h>

// Problem constants: B=32, S=4096, H=512, E=512
typedef __attribute__((ext_vector_type(8))) short bf16x8;
typedef __attribute__((ext_vector_type(16))) float f32x16;

typedef __attribute__((address_space(3))) unsigned int lds_u32;
typedef __attribute__((address_space(1))) unsigned int glb_u32;

union frag_u { bf16x8 v; unsigned int u[4]; };

__device__ inline unsigned int cvt_pk_bf16(float lo, float hi){
  unsigned int r;
  asm("v_cvt_pk_bf16_f32 %0, %1, %2" : "=v"(r) : "v"(lo), "v"(hi));
  return r;
}
__device__ inline bf16x8 pack8(float4 a, float4 b){
  union { unsigned int u[4]; bf16x8 v; } r;
  r.u[0]=cvt_pk_bf16(a.x,a.y); r.u[1]=cvt_pk_bf16(a.z,a.w);
  r.u[2]=cvt_pk_bf16(b.x,b.y); r.u[3]=cvt_pk_bf16(b.z,b.w);
  return r.v;
}
__device__ inline float fast_tanh(float x){
  float e = __builtin_amdgcn_exp2f(x * 2.8853900817779268f);
  return 1.0f - 2.0f * __builtin_amdgcn_rcpf(e + 1.0f);
}
#define PIN8(F) asm volatile("" : "+v"((F).u[0]), "+v"((F).u[1]), \
                                  "+v"((F).u[2]), "+v"((F).u[3]))
#define LOG2E 1.4426950408889634f

// ---- K0: We [512][512] f32 -> bf16 fragment images for mfma_32x32x16.
__global__ __launch_bounds__(256) void we_conv(const float* __restrict__ We,
                                               uint4* __restrict__ weFrag){
  int gid = blockIdx.x * 256 + threadIdx.x;   // 32768 = 16 nc x 32 t x 64 lanes
  int l  = gid & 63;
  int nc = gid >> 11;
  int t  = (gid >> 6) & 31;
  int colv = nc*32 + (l & 31);
  int k = t*16 + (l >> 5)*8;
  const float4* src = (const float4*)(We + colv*512 + k);
  float4 f0 = src[0], f1 = src[1];
  weFrag[gid] = make_uint4(cvt_pk_bf16(f0.x,f0.y), cvt_pk_bf16(f0.z,f0.w),
                           cvt_pk_bf16(f1.x,f1.y), cvt_pk_bf16(f1.z,f1.w));
}

// ---- K1: gd[b][k] = h[b,:]·Wd[k,:] + bd[k] + be[k]
__global__ __launch_bounds__(256) void gd_kernel(const float* __restrict__ hvec,
                                                 const float* __restrict__ Wd,
                                                 const float* __restrict__ bd,
                                                 const float* __restrict__ be,
                                                 float* __restrict__ gd){
  __shared__ float hs[512];
  int b = blockIdx.x >> 2, kc = blockIdx.x & 3;
  int tid = threadIdx.x;
  hs[tid]       = hvec[b*512 + tid];
  hs[tid + 256] = hvec[b*512 + 256 + tid];
  __syncthreads();
  int k  = kc*128 + (tid >> 1);
  int hh = (tid & 1) * 256;
  const float4* wrow = (const float4*)(Wd + (size_t)k*512 + hh);
  const float4* hv4  = (const float4*)(hs + hh);
  float acc = 0.f;
  #pragma unroll 8
  for (int i = 0; i < 64; ++i){
    float4 w = wrow[i]; float4 u = hv4[i];
    acc += w.x*u.x + w.y*u.y + w.z*u.z + w.w*u.w;
  }
  acc += __shfl_xor(acc, 1);
  if ((tid & 1) == 0) gd[b*512 + k] = acc + bd[k] + be[k];
}

// ---- K2: fused scores + flash-style partial context.
// Main loop identical to the round-6 165us kernel. Epilogue: block-local
// softmax partials (M_blk, S_blk) and unnormalized ctp[512] computed from
// the register-resident A-fragments (via a 2-pass LDS transpose into the
// freed B buffers). Eliminates the 256MB ctx re-read of ct_partial.
__global__ __launch_bounds__(256, 2) void score_kernel(
    const float* __restrict__ ctx, const uint4* __restrict__ weFrag,
    const float* __restrict__ gd, const float* __restrict__ Wv,
    float* __restrict__ scores, float* __restrict__ ctp,
    float* __restrict__ MS){
  __shared__ char lds[2*32768 + 4096];       // 68 KiB: B dbuf + gdwv
  __shared__ float sc_lds[128];
  __shared__ float w_lds[128];
  __shared__ float red2[2];
  char* ldsB = lds;
  float* gdwv = (float*)(lds + 65536);       // [512 gd][512 Wv]

  const int tid  = threadIdx.x;
  const int wid  = tid >> 6;
  const int lane = tid & 63;
  const int bid  = blockIdx.x;
  const int row0 = bid * 128;
  const int b    = bid >> 5;                 // 32 blocks per batch row
  const int col  = lane & 31;
  const int hi   = lane >> 5;

  #define ISSUE(NC, BUF) do { \
    const char* _g = (const char*)weFrag + (size_t)(NC)*32768 + wid*8192 + lane*16; \
    char* _l = ldsB + (BUF)*32768 + wid*8192; \
    _Pragma("unroll") \
    for (int _i = 0; _i < 8; ++_i) \
      __builtin_amdgcn_global_load_lds((const glb_u32*)(_g + _i*1024), \
                                       (lds_u32*)(_l + _i*1024), 16, 0, 0); \
  } while(0)

  ISSUE(0, 0);                               // chunk 0 in flight ASAP

  if (tid < 128) ((float4*)gdwv)[tid] = ((const float4*)(gd + b*512))[tid];
  else           ((float4*)gdwv)[tid] = ((const float4*)Wv)[tid - 128];

  // A-fragments: 32 k-steps, register/AGPR-resident, pinned.
  frag_u afrag[32];
  {
    const float4* ap = (const float4*)(ctx + (size_t)(row0 + wid*32 + col)*512 + hi*8);
    #pragma unroll
    for (int t = 0; t < 32; ++t){
      afrag[t].v = pack8(ap[t*4], ap[t*4 + 1]);
      PIN8(afrag[t]);
    }
  }

  asm volatile("s_waitcnt lgkmcnt(0)" ::: "memory");  // gdwv ds_writes done

  float sc[16];
  #pragma unroll
  for (int r = 0; r < 16; ++r) sc[r] = 0.f;

  for (int nc = 0; nc < 16; ++nc){
    asm volatile("s_waitcnt vmcnt(0)" ::: "memory");
    __builtin_amdgcn_s_barrier();
    if (nc < 15) ISSUE(nc + 1, (nc + 1) & 1);

    const char* bb = ldsB + (nc & 1)*32768 + lane*16;
    f32x16 accLo, accHi;
    #pragma unroll
    for (int r = 0; r < 16; ++r){ accLo[r] = 0.f; accHi[r] = 0.f; }

    frag_u c0, c1, c2, c3, n0, n1, n2, n3;
    c0.v = *(const bf16x8*)(bb +  0*1024);
    c1.v = *(const bf16x8*)(bb +  8*1024);
    c2.v = *(const bf16x8*)(bb + 16*1024);
    c3.v = *(const bf16x8*)(bb + 24*1024);
    PIN8(c0); PIN8(c1); PIN8(c2); PIN8(c3);

    #pragma unroll
    for (int g = 0; g < 8; ++g){
      if (g < 7){
        n0.v = *(const bf16x8*)(bb + (g + 1     )*1024);
        n1.v = *(const bf16x8*)(bb + (g + 1 +  8)*1024);
        n2.v = *(const bf16x8*)(bb + (g + 1 + 16)*1024);
        n3.v = *(const bf16x8*)(bb + (g + 1 + 24)*1024);
      }
      __builtin_amdgcn_s_setprio(1);
      accLo = __builtin_amdgcn_mfma_f32_32x32x16_bf16(afrag[g     ].v, c0.v, accLo, 0, 0, 0);
      accHi = __builtin_amdgcn_mfma_f32_32x32x16_bf16(afrag[g + 16].v, c2.v, accHi, 0, 0, 0);
      accLo = __builtin_amdgcn_mfma_f32_32x32x16_bf16(afrag[g +  8].v, c1.v, accLo, 0, 0, 0);
      accHi = __builtin_amdgcn_mfma_f32_32x32x16_bf16(afrag[g + 24].v, c3.v, accHi, 0, 0, 0);
      __builtin_amdgcn_s_setprio(0);
      if (g < 7){
        PIN8(n0); PIN8(n1); PIN8(n2); PIN8(n3);
        c0 = n0; c1 = n1; c2 = n2; c3 = n3;
      }
    }

    float gdv = gdwv[nc*32 + col];
    float wvv = gdwv[512 + nc*32 + col];
    #pragma unroll
    for (int r = 0; r < 16; ++r)
      sc[r] += fast_tanh(accLo[r] + accHi[r] + gdv) * wvv;
  }
  #undef ISSUE

  // reduce over the 32 output columns
  #pragma unroll
  for (int r = 0; r < 16; ++r){
    #pragma unroll
    for (int m = 1; m <= 16; m <<= 1) sc[r] += __shfl_xor(sc[r], m);
  }
  if (col == 0){
    float* so = scores + row0 + wid*32 + 4*hi;
    #pragma unroll
    for (int r = 0; r < 16; ++r){
      int rr = (r & 3) + 8*(r >> 2);
      so[rr] = sc[r];                         // global (for weights kernel)
      sc_lds[wid*32 + 4*hi + rr] = sc[r];     // block-local
    }
  }
  __syncthreads();                            // sc_lds ready; ldsB reads done

  // ---- block-local softmax partials
  float M = -1e30f;
  {
    const float4* s4 = (const float4*)sc_lds;
    #pragma unroll
    for (int i = 0; i < 32; ++i){
      float4 v = s4[i];
      M = fmaxf(M, fmaxf(fmaxf(v.x, v.y), fmaxf(v.z, v.w)));
    }
  }
  if (tid < 128){
    float w = __builtin_amdgcn_exp2f((sc_lds[tid] - M) * LOG2E);
    w_lds[tid] = w;
    #pragma unroll
    for (int o = 1; o < 64; o <<= 1) w += __shfl_xor(w, o);
    if ((tid & 63) == 0) red2[tid >> 6] = w;
  }
  __syncthreads();
  float S_blk = red2[0] + red2[1];

  // ---- ctp[h] = sum_r w_r * A[r,h], two 64-row passes through ldsB
  float ctpA = 0.f, ctpB = 0.f;               // h = 2*tid, 2*tid+1
  #pragma unroll
  for (int p = 0; p < 2; ++p){
    if ((wid >> 1) == p){                     // waves 2p,2p+1 own these rows
      int rl = (wid & 1)*32 + col;            // local row 0..63
      char* dst = ldsB + rl*1024;
      int swz = (rl & 7) << 4;
      #pragma unroll
      for (int t = 0; t < 32; ++t)
        *(uint4*)(dst + ((t*32 + hi*16) ^ swz)) = *(uint4*)&afrag[t].u[0];
    }
    __syncthreads();
    const float* wp = w_lds + p*64;
    #pragma unroll 8
    for (int r = 0; r < 64; ++r){
      unsigned int u = *(const unsigned int*)(ldsB + r*1024 + ((tid*4) ^ ((r & 7) << 4)));
      float cw = wp[r];
      union { unsigned int q; float f; } flo, fhi;
      flo.q = u << 16;
      fhi.q = u & 0xffff0000u;
      ctpA += cw * flo.f;
      ctpB += cw * fhi.f;
    }
    __syncthreads();
  }
  ((float2*)(ctp + (size_t)bid*512))[tid] = make_float2(ctpA, ctpB);
  if (tid == 0){ MS[2*bid] = M; MS[2*bid + 1] = S_blk; }
}

// ---- K3: combine 32 chunk-partials per batch -> ct[b][512], mbuf[b]={M,1/den}
__global__ __launch_bounds__(256) void combine_kernel(const float* __restrict__ ctp,
                                                      const float* __restrict__ MS,
                                                      float* __restrict__ ct,
                                                      float* __restrict__ mbuf){
  __shared__ float wsh[32];
  __shared__ float msh[2];
  int b = blockIdx.x, tid = threadIdx.x;
  if (tid < 64){
    int i = tid & 31;
    float Mi = MS[(b*32 + i)*2];
    float Si = MS[(b*32 + i)*2 + 1];
    float M = Mi;
    #pragma unroll
    for (int o = 1; o < 32; o <<= 1) M = fmaxf(M, __shfl_xor(M, o));
    float w = __builtin_amdgcn_exp2f((Mi - M) * LOG2E);
    float d = w * Si;
    #pragma unroll
    for (int o = 1; o < 32; o <<= 1) d += __shfl_xor(d, o);
    if (tid < 32) wsh[i] = w;
    if (tid == 0){ msh[0] = M; msh[1] = 1.0f / d; }
  }
  __syncthreads();
  float invd = msh[1];
  float a0 = 0.f, a1 = 0.f;
  #pragma unroll
  for (int i = 0; i < 32; ++i){
    float2 v = ((const float2*)(ctp + (size_t)(b*32 + i)*512))[tid];
    float w = wsh[i];
    a0 += w * v.x; a1 += w * v.y;
  }
  ((float2*)(ct + b*512))[tid] = make_float2(a0 * invd, a1 * invd);
  if (tid == 0){ mbuf[2*b] = msh[0]; mbuf[2*b + 1] = invd; }
}

// ---- K4: weights[b][s] = exp(score - M_b) * inv_denom
__global__ __launch_bounds__(256) void weights_kernel(const float* __restrict__ scores,
                                                      const float* __restrict__ mbuf,
                                                      float* __restrict__ weights){
  int b = blockIdx.x, tid = threadIdx.x;
  float M = mbuf[2*b], invd = mbuf[2*b + 1];
  const float4* src = (const float4*)(scores + b*4096);
  float4* dst = (float4*)(weights + b*4096);
  #pragma unroll
  for (int i = 0; i < 4; ++i){
    float4 v = src[tid + i*256];
    v.x = __builtin_amdgcn_exp2f((v.x - M) * LOG2E) * invd;
    v.y = __builtin_amdgcn_exp2f((v.y - M) * LOG2E) * invd;
    v.z = __builtin_amdgcn_exp2f((v.z - M) * LOG2E) * invd;
    v.w = __builtin_amdgcn_exp2f((v.w - M) * LOG2E) * invd;
    dst[tid + i*256] = v;
  }
}

// ---- K5: r_t = [c_t,h,x]·Wr^T + br; maxout pairs -> output [32][512]
__global__ __launch_bounds__(256) void final_kernel(
    const float* __restrict__ ct, const float* __restrict__ hvec,
    const float* __restrict__ x, const float* __restrict__ Wr,
    const float* __restrict__ br, float* __restrict__ out){
  __shared__ float xs[8][1536];
  int bt = blockIdx.x >> 4;
  int it = blockIdx.x & 15;
  int tid = threadIdx.x;
  int b0 = bt * 8;
  for (int idx = tid; idx < 8*1536; idx += 256){
    int bl = idx / 1536, j = idx % 1536;
    int b = b0 + bl;
    float v = (j < 512) ? ct[b*512 + j]
            : (j < 1024) ? hvec[b*512 + (j - 512)]
            : x[b*512 + (j - 1024)];
    xs[bl][j] = v;
  }
  __syncthreads();
  int i = it*64 + (tid & 63);
  int bl0 = (tid >> 6) * 2;
  const float4* wrow = (const float4*)(Wr + (size_t)i*1536);
  const float4* x0 = (const float4*)xs[bl0];
  const float4* x1 = (const float4*)xs[bl0 + 1];
  float a0 = 0.f, a1 = 0.f;
  #pragma unroll 4
  for (int k = 0; k < 384; ++k){
    float4 w = wrow[k];
    float4 u0 = x0[k], u1 = x1[k];
    a0 += w.x*u0.x + w.y*u0.y + w.z*u0.z + w.w*u0.w;
    a1 += w.x*u1.x + w.y*u1.y + w.z*u1.z + w.w*u1.w;
  }
  float bias = br[i];
  a0 += bias; a1 += bias;
  float n0 = __shfl_xor(a0, 1);
  float n1 = __shfl_xor(a1, 1);
  if ((tid & 1) == 0){
    out[(b0 + bl0    )*512 + (i >> 1)] = fmaxf(a0, n0);
    out[(b0 + bl0 + 1)*512 + (i >> 1)] = fmaxf(a1, n1);
  }
}

extern "C" void kernel_launch(void* const* d_in, const int* in_sizes, int n_in,
                              void* d_out, int out_size, void* d_ws, size_t ws_size,
                              hipStream_t stream){
  const float* ctx  = (const float*)d_in[0];
  const float* hvec = (const float*)d_in[1];
  const float* x    = (const float*)d_in[2];
  const float* We   = (const float*)d_in[3];
  const float* be   = (const float*)d_in[4];
  const float* Wd   = (const float*)d_in[5];
  const float* bd   = (const float*)d_in[6];
  const float* Wv   = (const float*)d_in[7];
  // d_in[8] = bv: dropped (softmax shift-invariance)
  const float* Wr   = (const float*)d_in[9];
  const float* br   = (const float*)d_in[10];

  float* out     = (float*)d_out;        // output [32][512]
  float* weights = out + 32*512;         // weights [32][4096]

  char* ws = (char*)d_ws;
  char* weFrag   = ws;                                   // 512 KiB
  float* scores  = (float*)(ws + (512 << 10));           // 512 KiB
  float* ctp     = (float*)(ws + (1024 << 10));          // 2 MiB (1024x512 f32)
  float* MS      = (float*)(ws + (3 << 20));             // 8 KiB
  float* mbuf    = (float*)(ws + (3 << 20) + (16 << 10)); // 256 B
  float* ct      = (float*)(ws + (3 << 20) + (32 << 10)); // 64 KiB
  float* gd      = (float*)(ws + (3 << 20) + (96 << 10)); // 2 KiB... 64 KiB region

  we_conv<<<128, 256, 0, stream>>>(We, (uint4*)weFrag);
  gd_kernel<<<128, 256, 0, stream>>>(hvec, Wd, bd, be, gd);
  score_kernel<<<1024, 256, 0, stream>>>(ctx, (const uint4*)weFrag, gd, Wv,
                                         scores, ctp, MS);
  combine_kernel<<<32, 256, 0, stream>>>(ctp, MS, ct, mbuf);
  weights_kernel<<<32, 256, 0, stream>>>(scores, mbuf, weights);
  final_kernel<<<64, 256, 0, stream>>>(ct, hvec, x, Wr, br, out);
}

// Round 9
// 200.239 us; speedup vs baseline: 1.9399x; 1.0042x over previous
//
#include <hip/hip_runtime.h>

// Problem constants: B=32, S=4096, H=512, E=512
typedef __attribute__((ext_vector_type(8))) short bf16x8;
typedef __attribute__((ext_vector_type(16))) float f32x16;

typedef __attribute__((address_space(3))) unsigned int lds_u32;
typedef __attribute__((address_space(1))) unsigned int glb_u32;

union frag_u { bf16x8 v; unsigned int u[4]; };

__device__ inline unsigned int cvt_pk_bf16(float lo, float hi){
  unsigned int r;
  asm("v_cvt_pk_bf16_f32 %0, %1, %2" : "=v"(r) : "v"(lo), "v"(hi));
  return r;
}
__device__ inline bf16x8 pack8(float4 a, float4 b){
  union { unsigned int u[4]; bf16x8 v; } r;
  r.u[0]=cvt_pk_bf16(a.x,a.y); r.u[1]=cvt_pk_bf16(a.z,a.w);
  r.u[2]=cvt_pk_bf16(b.x,b.y); r.u[3]=cvt_pk_bf16(b.z,b.w);
  return r.v;
}
__device__ inline float fast_tanh(float x){
  float e = __builtin_amdgcn_exp2f(x * 2.8853900817779268f);
  return 1.0f - 2.0f * __builtin_amdgcn_rcpf(e + 1.0f);
}
#define PIN8(F) asm volatile("" : "+v"((F).u[0]), "+v"((F).u[1]), \
                                  "+v"((F).u[2]), "+v"((F).u[3]))
#define LOG2E 1.4426950408889634f

// ---- K0: We [512][512] f32 -> bf16 fragment images for mfma_32x32x16.
__global__ __launch_bounds__(256) void we_conv(const float* __restrict__ We,
                                               uint4* __restrict__ weFrag){
  int gid = blockIdx.x * 256 + threadIdx.x;   // 32768 = 16 nc x 32 t x 64 lanes
  int l  = gid & 63;
  int nc = gid >> 11;
  int t  = (gid >> 6) & 31;
  int colv = nc*32 + (l & 31);
  int k = t*16 + (l >> 5)*8;
  const float4* src = (const float4*)(We + colv*512 + k);
  float4 f0 = src[0], f1 = src[1];
  weFrag[gid] = make_uint4(cvt_pk_bf16(f0.x,f0.y), cvt_pk_bf16(f0.z,f0.w),
                           cvt_pk_bf16(f1.x,f1.y), cvt_pk_bf16(f1.z,f1.w));
}

// ---- K1: gd[b][k] = h[b,:]·Wd[k,:] + bd[k] + be[k]
__global__ __launch_bounds__(256) void gd_kernel(const float* __restrict__ hvec,
                                                 const float* __restrict__ Wd,
                                                 const float* __restrict__ bd,
                                                 const float* __restrict__ be,
                                                 float* __restrict__ gd){
  __shared__ float hs[512];
  int b = blockIdx.x >> 2, kc = blockIdx.x & 3;
  int tid = threadIdx.x;
  hs[tid]       = hvec[b*512 + tid];
  hs[tid + 256] = hvec[b*512 + 256 + tid];
  __syncthreads();
  int k  = kc*128 + (tid >> 1);
  int hh = (tid & 1) * 256;
  const float4* wrow = (const float4*)(Wd + (size_t)k*512 + hh);
  const float4* hv4  = (const float4*)(hs + hh);
  float acc = 0.f;
  #pragma unroll 8
  for (int i = 0; i < 64; ++i){
    float4 w = wrow[i]; float4 u = hv4[i];
    acc += w.x*u.x + w.y*u.y + w.z*u.z + w.w*u.w;
  }
  acc += __shfl_xor(acc, 1);
  if ((tid & 1) == 0) gd[b*512 + k] = acc + bd[k] + be[k];
}

// ---- K2: fused scores + flash-style partial context.
// Identical to round-8 except the k-column chunk schedule is STAGGERED:
// block bid starts at chunk (bid & 15) and wraps. Breaks the chip-wide
// L2 set hot-spot (all blocks reading the same 32KB in lockstep).
__global__ __launch_bounds__(256, 2) void score_kernel(
    const float* __restrict__ ctx, const uint4* __restrict__ weFrag,
    const float* __restrict__ gd, const float* __restrict__ Wv,
    float* __restrict__ scores, float* __restrict__ ctp,
    float* __restrict__ MS){
  __shared__ char lds[2*32768 + 4096];       // 68 KiB: B dbuf + gdwv
  __shared__ float sc_lds[128];
  __shared__ float w_lds[128];
  __shared__ float red2[2];
  char* ldsB = lds;
  float* gdwv = (float*)(lds + 65536);       // [512 gd][512 Wv]

  const int tid  = threadIdx.x;
  const int wid  = tid >> 6;
  const int lane = tid & 63;
  const int bid  = blockIdx.x;
  const int row0 = bid * 128;
  const int b    = bid >> 5;                 // 32 blocks per batch row
  const int col  = lane & 31;
  const int hi   = lane >> 5;
  const int st   = bid & 15;                 // staggered start chunk

  #define ISSUE(NC, BUF) do { \
    const char* _g = (const char*)weFrag + (size_t)(NC)*32768 + wid*8192 + lane*16; \
    char* _l = ldsB + (BUF)*32768 + wid*8192; \
    _Pragma("unroll") \
    for (int _i = 0; _i < 8; ++_i) \
      __builtin_amdgcn_global_load_lds((const glb_u32*)(_g + _i*1024), \
                                       (lds_u32*)(_l + _i*1024), 16, 0, 0); \
  } while(0)

  ISSUE(st, 0);                              // first chunk in flight ASAP

  if (tid < 128) ((float4*)gdwv)[tid] = ((const float4*)(gd + b*512))[tid];
  else           ((float4*)gdwv)[tid] = ((const float4*)Wv)[tid - 128];

  // A-fragments: 32 k-steps, register/AGPR-resident, pinned.
  frag_u afrag[32];
  {
    const float4* ap = (const float4*)(ctx + (size_t)(row0 + wid*32 + col)*512 + hi*8);
    #pragma unroll
    for (int t = 0; t < 32; ++t){
      afrag[t].v = pack8(ap[t*4], ap[t*4 + 1]);
      PIN8(afrag[t]);
    }
  }

  asm volatile("s_waitcnt lgkmcnt(0)" ::: "memory");  // gdwv ds_writes done

  float sc[16];
  #pragma unroll
  for (int r = 0; r < 16; ++r) sc[r] = 0.f;

  for (int nc = 0; nc < 16; ++nc){
    const int cur = (st + nc) & 15;          // chunk id this phase
    asm volatile("s_waitcnt vmcnt(0)" ::: "memory");
    __builtin_amdgcn_s_barrier();
    if (nc < 15) ISSUE((cur + 1) & 15, (nc + 1) & 1);

    const char* bb = ldsB + (nc & 1)*32768 + lane*16;
    f32x16 accLo, accHi;
    #pragma unroll
    for (int r = 0; r < 16; ++r){ accLo[r] = 0.f; accHi[r] = 0.f; }

    frag_u c0, c1, c2, c3, n0, n1, n2, n3;
    c0.v = *(const bf16x8*)(bb +  0*1024);
    c1.v = *(const bf16x8*)(bb +  8*1024);
    c2.v = *(const bf16x8*)(bb + 16*1024);
    c3.v = *(const bf16x8*)(bb + 24*1024);
    PIN8(c0); PIN8(c1); PIN8(c2); PIN8(c3);

    #pragma unroll
    for (int g = 0; g < 8; ++g){
      if (g < 7){
        n0.v = *(const bf16x8*)(bb + (g + 1     )*1024);
        n1.v = *(const bf16x8*)(bb + (g + 1 +  8)*1024);
        n2.v = *(const bf16x8*)(bb + (g + 1 + 16)*1024);
        n3.v = *(const bf16x8*)(bb + (g + 1 + 24)*1024);
      }
      __builtin_amdgcn_s_setprio(1);
      accLo = __builtin_amdgcn_mfma_f32_32x32x16_bf16(afrag[g     ].v, c0.v, accLo, 0, 0, 0);
      accHi = __builtin_amdgcn_mfma_f32_32x32x16_bf16(afrag[g + 16].v, c2.v, accHi, 0, 0, 0);
      accLo = __builtin_amdgcn_mfma_f32_32x32x16_bf16(afrag[g +  8].v, c1.v, accLo, 0, 0, 0);
      accHi = __builtin_amdgcn_mfma_f32_32x32x16_bf16(afrag[g + 24].v, c3.v, accHi, 0, 0, 0);
      __builtin_amdgcn_s_setprio(0);
      if (g < 7){
        PIN8(n0); PIN8(n1); PIN8(n2); PIN8(n3);
        c0 = n0; c1 = n1; c2 = n2; c3 = n3;
      }
    }

    float gdv = gdwv[cur*32 + col];
    float wvv = gdwv[512 + cur*32 + col];
    #pragma unroll
    for (int r = 0; r < 16; ++r)
      sc[r] += fast_tanh(accLo[r] + accHi[r] + gdv) * wvv;
  }
  #undef ISSUE

  // reduce over the 32 output columns
  #pragma unroll
  for (int r = 0; r < 16; ++r){
    #pragma unroll
    for (int m = 1; m <= 16; m <<= 1) sc[r] += __shfl_xor(sc[r], m);
  }
  if (col == 0){
    float* so = scores + row0 + wid*32 + 4*hi;
    #pragma unroll
    for (int r = 0; r < 16; ++r){
      int rr = (r & 3) + 8*(r >> 2);
      so[rr] = sc[r];                         // global (for weights kernel)
      sc_lds[wid*32 + 4*hi + rr] = sc[r];     // block-local
    }
  }
  __syncthreads();                            // sc_lds ready; ldsB reads done

  // ---- block-local softmax partials
  float M = -1e30f;
  {
    const float4* s4 = (const float4*)sc_lds;
    #pragma unroll
    for (int i = 0; i < 32; ++i){
      float4 v = s4[i];
      M = fmaxf(M, fmaxf(fmaxf(v.x, v.y), fmaxf(v.z, v.w)));
    }
  }
  if (tid < 128){
    float w = __builtin_amdgcn_exp2f((sc_lds[tid] - M) * LOG2E);
    w_lds[tid] = w;
    #pragma unroll
    for (int o = 1; o < 64; o <<= 1) w += __shfl_xor(w, o);
    if ((tid & 63) == 0) red2[tid >> 6] = w;
  }
  __syncthreads();
  float S_blk = red2[0] + red2[1];

  // ---- ctp[h] = sum_r w_r * A[r,h], two 64-row passes through ldsB
  float ctpA = 0.f, ctpB = 0.f;               // h = 2*tid, 2*tid+1
  #pragma unroll
  for (int p = 0; p < 2; ++p){
    if ((wid >> 1) == p){                     // waves 2p,2p+1 own these rows
      int rl = (wid & 1)*32 + col;            // local row 0..63
      char* dst = ldsB + rl*1024;
      int swz = (rl & 7) << 4;
      #pragma unroll
      for (int t = 0; t < 32; ++t)
        *(uint4*)(dst + ((t*32 + hi*16) ^ swz)) = *(uint4*)&afrag[t].u[0];
    }
    __syncthreads();
    const float* wp = w_lds + p*64;
    #pragma unroll 8
    for (int r = 0; r < 64; ++r){
      unsigned int u = *(const unsigned int*)(ldsB + r*1024 + ((tid*4) ^ ((r & 7) << 4)));
      float cw = wp[r];
      union { unsigned int q; float f; } flo, fhi;
      flo.q = u << 16;
      fhi.q = u & 0xffff0000u;
      ctpA += cw * flo.f;
      ctpB += cw * fhi.f;
    }
    __syncthreads();
  }
  ((float2*)(ctp + (size_t)bid*512))[tid] = make_float2(ctpA, ctpB);
  if (tid == 0){ MS[2*bid] = M; MS[2*bid + 1] = S_blk; }
}

// ---- K3: combine 32 chunk-partials per batch -> ct[b][512], mbuf[b]={M,1/den}
__global__ __launch_bounds__(256) void combine_kernel(const float* __restrict__ ctp,
                                                      const float* __restrict__ MS,
                                                      float* __restrict__ ct,
                                                      float* __restrict__ mbuf){
  __shared__ float wsh[32];
  __shared__ float msh[2];
  int b = blockIdx.x, tid = threadIdx.x;
  if (tid < 64){
    int i = tid & 31;
    float Mi = MS[(b*32 + i)*2];
    float Si = MS[(b*32 + i)*2 + 1];
    float M = Mi;
    #pragma unroll
    for (int o = 1; o < 32; o <<= 1) M = fmaxf(M, __shfl_xor(M, o));
    float w = __builtin_amdgcn_exp2f((Mi - M) * LOG2E);
    float d = w * Si;
    #pragma unroll
    for (int o = 1; o < 32; o <<= 1) d += __shfl_xor(d, o);
    if (tid < 32) wsh[i] = w;
    if (tid == 0){ msh[0] = M; msh[1] = 1.0f / d; }
  }
  __syncthreads();
  float invd = msh[1];
  float a0 = 0.f, a1 = 0.f;
  #pragma unroll
  for (int i = 0; i < 32; ++i){
    float2 v = ((const float2*)(ctp + (size_t)(b*32 + i)*512))[tid];
    float w = wsh[i];
    a0 += w * v.x; a1 += w * v.y;
  }
  ((float2*)(ct + b*512))[tid] = make_float2(a0 * invd, a1 * invd);
  if (tid == 0){ mbuf[2*b] = msh[0]; mbuf[2*b + 1] = invd; }
}

// ---- K4: weights[b][s] = exp(score - M_b) * inv_denom
__global__ __launch_bounds__(256) void weights_kernel(const float* __restrict__ scores,
                                                      const float* __restrict__ mbuf,
                                                      float* __restrict__ weights){
  int b = blockIdx.x, tid = threadIdx.x;
  float M = mbuf[2*b], invd = mbuf[2*b + 1];
  const float4* src = (const float4*)(scores + b*4096);
  float4* dst = (float4*)(weights + b*4096);
  #pragma unroll
  for (int i = 0; i < 4; ++i){
    float4 v = src[tid + i*256];
    v.x = __builtin_amdgcn_exp2f((v.x - M) * LOG2E) * invd;
    v.y = __builtin_amdgcn_exp2f((v.y - M) * LOG2E) * invd;
    v.z = __builtin_amdgcn_exp2f((v.z - M) * LOG2E) * invd;
    v.w = __builtin_amdgcn_exp2f((v.w - M) * LOG2E) * invd;
    dst[tid + i*256] = v;
  }
}

// ---- K5: r_t = [c_t,h,x]·Wr^T + br; maxout pairs -> output [32][512]
__global__ __launch_bounds__(256) void final_kernel(
    const float* __restrict__ ct, const float* __restrict__ hvec,
    const float* __restrict__ x, const float* __restrict__ Wr,
    const float* __restrict__ br, float* __restrict__ out){
  __shared__ float xs[8][1536];
  int bt = blockIdx.x >> 4;
  int it = blockIdx.x & 15;
  int tid = threadIdx.x;
  int b0 = bt * 8;
  for (int idx = tid; idx < 8*1536; idx += 256){
    int bl = idx / 1536, j = idx % 1536;
    int b = b0 + bl;
    float v = (j < 512) ? ct[b*512 + j]
            : (j < 1024) ? hvec[b*512 + (j - 512)]
            : x[b*512 + (j - 1024)];
    xs[bl][j] = v;
  }
  __syncthreads();
  int i = it*64 + (tid & 63);
  int bl0 = (tid >> 6) * 2;
  const float4* wrow = (const float4*)(Wr + (size_t)i*1536);
  const float4* x0 = (const float4*)xs[bl0];
  const float4* x1 = (const float4*)xs[bl0 + 1];
  float a0 = 0.f, a1 = 0.f;
  #pragma unroll 4
  for (int k = 0; k < 384; ++k){
    float4 w = wrow[k];
    float4 u0 = x0[k], u1 = x1[k];
    a0 += w.x*u0.x + w.y*u0.y + w.z*u0.z + w.w*u0.w;
    a1 += w.x*u1.x + w.y*u1.y + w.z*u1.z + w.w*u1.w;
  }
  float bias = br[i];
  a0 += bias; a1 += bias;
  float n0 = __shfl_xor(a0, 1);
  float n1 = __shfl_xor(a1, 1);
  if ((tid & 1) == 0){
    out[(b0 + bl0    )*512 + (i >> 1)] = fmaxf(a0, n0);
    out[(b0 + bl0 + 1)*512 + (i >> 1)] = fmaxf(a1, n1);
  }
}

extern "C" void kernel_launch(void* const* d_in, const int* in_sizes, int n_in,
                              void* d_out, int out_size, void* d_ws, size_t ws_size,
                              hipStream_t stream){
  const float* ctx  = (const float*)d_in[0];
  const float* hvec = (const float*)d_in[1];
  const float* x    = (const float*)d_in[2];
  const float* We   = (const float*)d_in[3];
  const float* be   = (const float*)d_in[4];
  const float* Wd   = (const float*)d_in[5];
  const float* bd   = (const float*)d_in[6];
  const float* Wv   = (const float*)d_in[7];
  // d_in[8] = bv: dropped (softmax shift-invariance)
  const float* Wr   = (const float*)d_in[9];
  const float* br   = (const float*)d_in[10];

  float* out     = (float*)d_out;        // output [32][512]
  float* weights = out + 32*512;         // weights [32][4096]

  char* ws = (char*)d_ws;
  char* weFrag   = ws;                                   // 512 KiB
  float* scores  = (float*)(ws + (512 << 10));           // 512 KiB
  float* ctp     = (float*)(ws + (1024 << 10));          // 2 MiB (1024x512 f32)
  float* MS      = (float*)(ws + (3 << 20));             // 8 KiB
  float* mbuf    = (float*)(ws + (3 << 20) + (16 << 10)); // 256 B
  float* ct      = (float*)(ws + (3 << 20) + (32 << 10)); // 64 KiB
  float* gd      = (float*)(ws + (3 << 20) + (96 << 10)); // 64 KiB region

  we_conv<<<128, 256, 0, stream>>>(We, (uint4*)weFrag);
  gd_kernel<<<128, 256, 0, stream>>>(hvec, Wd, bd, be, gd);
  score_kernel<<<1024, 256, 0, stream>>>(ctx, (const uint4*)weFrag, gd, Wv,
                                         scores, ctp, MS);
  combine_kernel<<<32, 256, 0, stream>>>(ctp, MS, ct, mbuf);
  weights_kernel<<<32, 256, 0, stream>>>(scores, mbuf, weights);
  final_kernel<<<64, 256, 0, stream>>>(ct, hvec, x, Wr, br, out);
}